// Round 12
// baseline (1471.352 us; speedup 1.0000x reference)
//
#include <hip/hip_runtime.h>

// MSDNet on gfx950 — round 23: mega-kernel race fix. R22 failed correctness:
// the flag wait ran AFTER the plain-load pipeline, so plain reads of
// "immutable" pairs at rows y+-D_I had no happens-before edge to their
// producers (earlier depths waited different row offsets). First plain read
// could fill L2 with a pre-merge line -> stale forever. FIX: flag wait moved
// to the TOP of the depth body. flag(I-1, y+-D)>=2 + per-row program order +
// producer vmcnt(0) ==> all writes to those rows at depths <= I-1 are at the
// coherent point before ANY depth-I read; every first L2 fill of an
// immutable line is post-completion; the single mutable pair (NP-1) is read
// via system-scope loads (never cached). No barriers, no cache-maintenance
// ops (R13/R16 failure class), no XCD assumptions. Coop launch (512x512,
// (512,4) => 2 blk/CU co-resident). Fallback: R18-config 31-launch path
// (380.6us verified). Accumulation order unchanged => bit-identical.

#define MSD_DEPTH 30
#define NB 4
#define IH 512
#define IW 512
#define HALO 16
#define WPp (IW + 2 * HALO)               /* 544 u32 per row */
#define HPp (IH + 2 * HALO)               /* 544 rows */
#define PLANE_U ((size_t)WPp * HPp)       /* u32 per subplane */
#define PSTR ((size_t)NB * PLANE_U)       /* pair stride (u32) */
#define NPAIR 15
#define NPIX (NB * IH * IW)
#define FLAGS_OFF ((size_t)18 << 20)      /* u32 offset: 72 MB (feats end ~71 MB) */
#define NFLAGS (MSD_DEPTH * NB * IH)      /* 61440 */
#define WPK_OFF ((size_t)20 << 20)        /* u32 offset: 80 MB into ws */
#define ZSTRIPS (32 * (WPp / 4) * NPAIR * NB)   /* top/bot: 261120 uint4 */
#define SSTRIPS (512 * 8 * NPAIR * NB)          /* sides:   245760 uint4 */
#define TOTZ (ZSTRIPS + SSTRIPS)

typedef _Float16 h2v __attribute__((ext_vector_type(2)));
typedef unsigned int u32;

__device__ __forceinline__ float fdot2u(u32 a, u32 b, float c) {
#if __has_builtin(__builtin_amdgcn_fdot2)
    return __builtin_amdgcn_fdot2(__builtin_bit_cast(h2v, a),
                                  __builtin_bit_cast(h2v, b), c, false);
#else
    h2v x = __builtin_bit_cast(h2v, a), y = __builtin_bit_cast(h2v, b);
    return c + (float)x[0] * (float)y[0] + (float)x[1] * (float)y[1];
#endif
}

__device__ __forceinline__ u32 aload_sys(const u32* p) {
    return __hip_atomic_load(p, __ATOMIC_RELAXED, __HIP_MEMORY_SCOPE_SYSTEM);
}
__device__ __forceinline__ void astore_sys(u32* p, u32 v) {
    __hip_atomic_store(p, v, __ATOMIC_RELAXED, __HIP_MEMORY_SCOPE_SYSTEM);
}

// ---------------------------------------------------------------------------
// Preamble: pack weights + zero halos + zero flags + scale input.
// ---------------------------------------------------------------------------
__global__ __launch_bounds__(256) void preamble_kernel(const float* __restrict__ x,
                                                       const float* __restrict__ Wmsd,
                                                       const float* __restrict__ convW,
                                                       u32* __restrict__ feats,
                                                       u32* __restrict__ wpk,
                                                       u32* __restrict__ cpk,
                                                       const float* __restrict__ sw,
                                                       const float* __restrict__ sb) {
    int idx = blockIdx.x * 256 + threadIdx.x;

    if (idx < NFLAGS) feats[FLAGS_OFF + idx] = 0u;

    if (idx < MSD_DEPTH * NPAIR * 9) {
        int I = idx / (NPAIR * 9);
        int rem = idx - I * (NPAIR * 9);
        int p = rem / 9, t = rem - p * 9;
        int NC = I + 1, c0 = 2 * p, c1 = 2 * p + 1;
        h2v pk;
        pk[0] = (_Float16)((c0 < NC) ? Wmsd[((size_t)I * MSD_DEPTH + c0) * 9 + t] : 0.f);
        pk[1] = (_Float16)((c1 < NC) ? Wmsd[((size_t)I * MSD_DEPTH + c1) * 9 + t] : 0.f);
        wpk[idx] = __builtin_bit_cast(u32, pk);
    }
    if (idx < NPAIR) {
        h2v pk;
        pk[0] = (_Float16)convW[2 * idx];
        pk[1] = (_Float16)convW[2 * idx + 1];
        cpk[idx] = __builtin_bit_cast(u32, pk);
    }

    if (idx < ZSTRIPS) {
        const int per = 32 * (WPp / 4); // 32 rows x 136 uint4 strips
        int sub = idx / per;
        int s = idx - sub * per;
        int rr = s / 136;
        int c4 = (s - rr * 136) * 4;
        int r = (rr < 16) ? rr : (IH + HALO) + (rr - 16);
        uint4 z = {0, 0, 0, 0};
        *(uint4*)(feats + (size_t)sub * PLANE_U + (size_t)r * WPp + c4) = z;
    } else if (idx < TOTZ) {
        int s = idx - ZSTRIPS;
        int sub = s >> 12;
        int rem = s & 4095;
        int r = HALO + (rem >> 3);
        int e = rem & 7;
        int c4 = (e < 4) ? (e * 4) : (IW + HALO + (e - 4) * 4);
        uint4 z = {0, 0, 0, 0};
        *(uint4*)(feats + (size_t)sub * PLANE_U + (size_t)r * WPp + c4) = z;
    }

    if (idx < NPIX / 8) {
        int pix = idx * 8;
        int b = pix >> 18;
        int y = (pix >> 9) & 511;
        int xx = pix & 511;
        const float sws = sw[0], sbs = sb[0];
        u32 v[8];
#pragma unroll
        for (int j = 0; j < 8; ++j) {
            _Float16 h = (_Float16)(x[pix + j] * sws + sbs);
            v[j] = (u32)__builtin_bit_cast(unsigned short, h);
        }
        u32* q = feats + (size_t)b * PLANE_U + (size_t)(y + HALO) * WPp + HALO + xx;
        *(uint4*)q = *(uint4*)&v[0];
        *(uint4*)(q + 4) = *(uint4*)&v[4];
    }
}

// ---------------------------------------------------------------------------
// Depth body. MEGA=false: exact R18-config behavior. MEGA=true: flag wait at
// TOP (orders ALL depth-I reads after depth-I-1 row completion), plain loads
// for immutable pairs, system-scope loads for the single mutable pair,
// system-scope write-through merge stores + flag release.
// ---------------------------------------------------------------------------
template <int I, bool MEGA>
__device__ __forceinline__ void depth_body(int b, int y, int xx, int lane,
                                           u32* __restrict__ feats,
                                           const u32* __restrict__ wpk,
                                           const u32* __restrict__ cpk,
                                           const float* __restrict__ bias,
                                           const float* __restrict__ convW,
                                           const float* __restrict__ convB,
                                           const float* __restrict__ soutw,
                                           const float* __restrict__ soutb,
                                           float* __restrict__ out,
                                           u32* __restrict__ flags) {
    constexpr int D = (I % 10) + 1;
    constexpr int NC = I + 1;
    constexpr int NP = (NC + 1) / 2;
    constexpr bool LAST = (I == MSD_DEPTH - 1);
    constexpr int C0 = (12 - D) >> 2;   // D<=4 -> 2, D<=8 -> 1, else 0
    constexpr int C1 = (15 + D) >> 2;   // D<=4 -> 4, D<=8 -> 5, else 6
    // The ONLY pair rewritten at depth I-1 is NP-1 (for I>=1); all others
    // completed at depths <= I-2 and are ordered by the flag chain below.
    constexpr bool HASAT = MEGA && (I >= 1);
    constexpr int NPP = HASAT ? NP - 1 : NP;   // plain (immutable) pairs

    // ---- ordering gate (MEGA): all reads below happen after rows y-D, y,
    // y+D completed depth I-1 (flag==2: both half-row waves released). ----
    if constexpr (HASAT) {
        if (lane == 0) {
            u32* fb = flags + ((size_t)(I - 1) * NB + b) * IH;
#pragma unroll
            for (int t = 0; t < 3; ++t) {
                int r = (t == 0) ? (y - D) : (t == 1) ? y : (y + D);
                if (r < 0 || r >= IH) continue;
                while (__hip_atomic_load(&fb[r], __ATOMIC_RELAXED,
                                         __HIP_MEMORY_SCOPE_SYSTEM) < 2u)
                    __builtin_amdgcn_s_sleep(2);
            }
        }
        asm volatile("" ::: "memory");
        __builtin_amdgcn_sched_barrier(0);
    }

    u32* const pb = feats + (size_t)b * PLANE_U + (size_t)(y + HALO) * WPp + HALO + xx;

    float acc[4], ydot[4];
#pragma unroll
    for (int j = 0; j < 4; ++j) { acc[j] = 0.f; ydot[j] = 0.f; }

    const u32* const wrb = wpk + (size_t)I * (NPAIR * 9);

    u32 A[3][28], B[3][28];   // named double buffers (SROA-promoted)

    auto load_pair = [&](u32 (*bp)[28], int p) {
        const u32* pp = pb + (size_t)p * PSTR;
#pragma unroll
        for (int r = 0; r < 3; ++r) {
            const u32* rp = pp + (ptrdiff_t)(r - 1) * (D * WPp);
#pragma unroll
            for (int c = C0; c <= C1; ++c)
                *(uint4*)&bp[r][4 * c] = *(const uint4*)(rp - 12 + 4 * c);
        }
    };

    auto load_pair_at = [&](u32 (*bp)[28], int p) {
        const u32* pp = pb + (size_t)p * PSTR;
#pragma unroll
        for (int r = 0; r < 3; ++r) {
            const u32* rp = pp + (ptrdiff_t)(r - 1) * (D * WPp) - 12;
#pragma unroll
            for (int c = C0; c <= C1; ++c)
#pragma unroll
                for (int j = 0; j < 4; ++j)
                    bp[r][4 * c + j] = aload_sys(rp + 4 * c + j);
        }
    };

    auto compute = [&](u32 (*bp)[28], int p) {
        const u32* wq = wrb + p * 9;    // wave-uniform -> s_load
        const u32 cw = LAST ? cpk[p] : 0u;
#pragma unroll
        for (int r = 0; r < 3; ++r) {
            const u32* s = bp[r];
            const u32 w0 = wq[r * 3 + 0], w1 = wq[r * 3 + 1], w2 = wq[r * 3 + 2];
#pragma unroll
            for (int k = 0; k < 4; ++k) {
                float a = acc[k];
                a = fdot2u(s[12 - D + k], w0, a);   // const idx taps
                a = fdot2u(s[12 + k],     w1, a);
                a = fdot2u(s[12 + D + k], w2, a);
                acc[k] = a;
            }
            if (LAST && r == 1) {
#pragma unroll
                for (int k = 0; k < 4; ++k) ydot[k] = fdot2u(s[12 + k], cw, ydot[k]);
            }
        }
    };

    // Plain 2-deep pipeline over immutable pairs [0, NPP).
    if constexpr (NPP > 0) {
        load_pair(A, 0);
        int p = 0;
        for (; p + 2 <= NPP; p += 2) {
            load_pair(B, p + 1);
            compute(A, p);
            if (p + 2 < NPP) load_pair(A, p + 2);
            compute(B, p + 1);
        }
        if (p < NPP) compute(A, p);
    }

    if constexpr (HASAT) {
        // The single mutable pair, read at the device-coherent point.
        load_pair_at(A, NP - 1);
        compute(A, NP - 1);
    }

    const float b0 = bias[I];
    if (!LAST) {
        // Merge h (channel NC) into pair NC>>1. NC odd: hi16; partner lo16 =
        // channel NC-1 = center row of pair NP-1 (last pair computed).
        u32 part[4];
        if constexpr ((NC & 1) != 0) {
            if constexpr (HASAT) {
#pragma unroll
                for (int j = 0; j < 4; ++j) part[j] = A[1][12 + j];
            } else {
                constexpr bool inA = (((NP - 1) & 1) == 0);
                const u32* s = inA ? A[1] : B[1];
#pragma unroll
                for (int j = 0; j < 4; ++j) part[j] = s[12 + j];
            }
        }
        u32 mg[4];
#pragma unroll
        for (int j = 0; j < 4; ++j) {
            float hh = acc[j] + b0;
            hh = hh > 0.f ? hh : 0.f;
            u32 h16 = (u32)__builtin_bit_cast(unsigned short, (_Float16)hh);
            if constexpr ((NC & 1) != 0)
                mg[j] = (part[j] & 0xFFFFu) | (h16 << 16);
            else
                mg[j] = h16;
        }
        u32* q = feats + (size_t)(NC >> 1) * PSTR + (size_t)b * PLANE_U +
                 (size_t)(y + HALO) * WPp + HALO + xx;
        if constexpr (MEGA) {
            astore_sys(q + 0, mg[0]);
            astore_sys(q + 1, mg[1]);
            astore_sys(q + 2, mg[2]);
            astore_sys(q + 3, mg[3]);
            asm volatile("s_waitcnt vmcnt(0)" ::: "memory");
            if (lane == 0)
                __hip_atomic_fetch_add(flags + ((size_t)I * NB + b) * IH + y, 1u,
                                       __ATOMIC_RELAXED, __HIP_MEMORY_SCOPE_SYSTEM);
        } else {
            *(uint4*)q = *(uint4*)&mg[0];
        }
    } else {
        const float cw30 = convW[MSD_DEPTH];
        const float cb = convB[0], ow = soutw[0], ob = soutb[0];
        float* q = out + ((size_t)b * IH + y) * IW + xx;
        float o[4];
#pragma unroll
        for (int j = 0; j < 4; ++j) {
            float hh = acc[j] + b0;
            hh = hh > 0.f ? hh : 0.f;
            float yv = ydot[j] + cw30 * hh + cb;
            o[j] = yv * ow + ob;
        }
        *(uint4*)q = *(uint4*)&o[0];
    }
}

// ---------------------------------------------------------------------------
// Legacy (fallback) depth kernel — R18 config (verified 380.6us).
// ---------------------------------------------------------------------------
template <int I>
__global__ __launch_bounds__(512, 4) void depth4_kernel(u32* __restrict__ feats,
                                                        const u32* __restrict__ wpk,
                                                        const u32* __restrict__ cpk,
                                                        const float* __restrict__ bias,
                                                        const float* __restrict__ convW,
                                                        const float* __restrict__ convB,
                                                        const float* __restrict__ soutw,
                                                        const float* __restrict__ soutb,
                                                        float* __restrict__ out) {
    const int tid = threadIdx.x;
    const int widx = tid >> 6, lane = tid & 63;
    const int bid = blockIdx.x;         // 512 blocks x 8 waves = 4096 half-rows
    const int xcd = bid & 7;            // XCD band swizzle (validated R4-R8)
    const int kk = bid >> 3;
    const int b = xcd >> 1;
    const int y = (xcd & 1) * 256 + kk * 4 + (widx >> 1);
    const int h = widx & 1;
    const int xx = h * 256 + lane * 4;
    depth_body<I, false>(b, y, xx, lane, feats, wpk, cpk, bias, convW, convB,
                         soutw, soutb, out, nullptr);
}

// ---------------------------------------------------------------------------
// Fused mega-kernel: 30 depth bodies, flag-pipelined, no barriers.
// ---------------------------------------------------------------------------
__global__ __launch_bounds__(512, 4) void msd_mega(u32* __restrict__ feats,
                                                   const u32* __restrict__ wpk,
                                                   const u32* __restrict__ cpk,
                                                   const float* __restrict__ bias,
                                                   const float* __restrict__ convW,
                                                   const float* __restrict__ convB,
                                                   const float* __restrict__ soutw,
                                                   const float* __restrict__ soutb,
                                                   float* __restrict__ out,
                                                   u32* __restrict__ flags) {
    const int tid = threadIdx.x;
    const int widx = tid >> 6, lane = tid & 63;
    const int bid = blockIdx.x;
    const int xcd = bid & 7;
    const int kk = bid >> 3;
    const int b = xcd >> 1;
    const int y = (xcd & 1) * 256 + kk * 4 + (widx >> 1);
    const int h = widx & 1;
    const int xx = h * 256 + lane * 4;

#define PH(I)                                                                  \
    depth_body<I, true>(b, y, xx, lane, feats, wpk, cpk, bias, convW, convB,   \
                        soutw, soutb, out, flags);
    PH(0)  PH(1)  PH(2)  PH(3)  PH(4)
    PH(5)  PH(6)  PH(7)  PH(8)  PH(9)
    PH(10) PH(11) PH(12) PH(13) PH(14)
    PH(15) PH(16) PH(17) PH(18) PH(19)
    PH(20) PH(21) PH(22) PH(23) PH(24)
    PH(25) PH(26) PH(27) PH(28) PH(29)
#undef PH
}

// ---------------------------------------------------------------------------
extern "C" void kernel_launch(void* const* d_in, const int* in_sizes, int n_in,
                              void* d_out, int out_size, void* d_ws, size_t ws_size,
                              hipStream_t stream) {
    const float* x     = (const float*)d_in[0];
    const float* Wmsd  = (const float*)d_in[1];
    const float* bias  = (const float*)d_in[2];
    const float* convW = (const float*)d_in[3];
    const float* convB = (const float*)d_in[4];
    const float* sinw  = (const float*)d_in[5];
    const float* sinb  = (const float*)d_in[6];
    const float* soutw = (const float*)d_in[7];
    const float* soutb = (const float*)d_in[8];
    float* out = (float*)d_out;

    u32* feats = (u32*)d_ws;                 // 15 pairs x 4 b x 544x544 u32 = 71 MB
    u32* flags = feats + FLAGS_OFF;          // 72 MB mark (gap before wpk)
    u32* wpk = feats + WPK_OFF;              // 80 MB offset
    u32* cpk = wpk + MSD_DEPTH * NPAIR * 9;

    preamble_kernel<<<(TOTZ + 255) / 256, 256, 0, stream>>>(x, Wmsd, convW,
                                                            feats, wpk, cpk,
                                                            sinw, sinb);

    void* args[] = {&feats, &wpk, &cpk, &bias, &convW, &convB,
                    &soutw, &soutb, &out, &flags};
    hipError_t rc = hipLaunchCooperativeKernel(msd_mega, dim3(512), dim3(512),
                                               args, 0u, stream);
    if (rc != hipSuccess) {
        (void)hipGetLastError();             // clear sticky error, legacy path
#define LNCH(I) depth4_kernel<I><<<512, 512, 0, stream>>>(feats, wpk, cpk, bias, convW, convB, soutw, soutb, out);
        LNCH(0)  LNCH(1)  LNCH(2)  LNCH(3)  LNCH(4)
        LNCH(5)  LNCH(6)  LNCH(7)  LNCH(8)  LNCH(9)
        LNCH(10) LNCH(11) LNCH(12) LNCH(13) LNCH(14)
        LNCH(15) LNCH(16) LNCH(17) LNCH(18) LNCH(19)
        LNCH(20) LNCH(21) LNCH(22) LNCH(23) LNCH(24)
        LNCH(25) LNCH(26) LNCH(27) LNCH(28) LNCH(29)
#undef LNCH
    }
}

// Round 13
// 740.313 us; speedup vs baseline: 1.9875x; 1.9875x over previous
//
#include <hip/hip_runtime.h>

// MSDNet on gfx950 — round 24: depth-PAIR fusion via redundant compute, not
// communication. R23's mega was correct but 1471us: system-scope dword
// traffic (write-through merges + uncached mutable-pair reads) = 1.9GB of
// uncoalesced HBM/L3 ops. Fusion-by-coherence is closed (R13/R16/R22/R23).
// This design fuses depths (I, I+1), I even, into one kernel with ZERO
// cross-block dependencies:
//  - phase 1: depth I computed for the block's 4 owned rows PLUS 2*D2 halo
//    rows (redundant across blocks); merged pair dwords stored to LDS;
//    owned rows also stored to global (consumed by the NEXT kernel only).
//  - phase 2: depth I+1 for owned rows; channels <= I from global
//    (immutable, kernel-boundary coherent), channel I+1 from LDS.
//  - safety of concurrent pair-I/2 traffic: only hi16 changes; phase-1
//    readers see it through a zero-padded weight (0 x finite = 0); phase-2
//    masks lo16 from regs; aligned dword loads don't tear. Plain loads/
//    stores everywhere; no atomics/fences/coop launch.
// Per-pixel tap+accumulation order unchanged => bit-identical numerics.
// 16 launches instead of 31 (~150us of launch overhead removed, ~+40us
// redundant compute). Layout: feats = 15 pairs (u32=2xf16) x 4b x 544x544;
// 512 blocks x 512 thr (4 owned rows/block, 4px/lane), XCD bands, (512,4).

#define MSD_DEPTH 30
#define NB 4
#define IH 512
#define IW 512
#define HALO 16
#define WPp (IW + 2 * HALO)               /* 544 u32 per row */
#define HPp (IH + 2 * HALO)               /* 544 rows */
#define PLANE_U ((size_t)WPp * HPp)       /* u32 per subplane */
#define PSTR ((size_t)NB * PLANE_U)       /* pair stride (u32) */
#define NPAIR 15
#define NPIX (NB * IH * IW)
#define WPK_OFF ((size_t)20 << 20)        /* u32 offset: 80 MB into ws */
#define ZSTRIPS (32 * (WPp / 4) * NPAIR * NB)   /* top/bot: 261120 uint4 */
#define SSTRIPS (512 * 8 * NPAIR * NB)          /* sides:   245760 uint4 */
#define TOTZ (ZSTRIPS + SSTRIPS)

typedef _Float16 h2v __attribute__((ext_vector_type(2)));
typedef unsigned int u32;

__device__ __forceinline__ float fdot2u(u32 a, u32 b, float c) {
#if __has_builtin(__builtin_amdgcn_fdot2)
    return __builtin_amdgcn_fdot2(__builtin_bit_cast(h2v, a),
                                  __builtin_bit_cast(h2v, b), c, false);
#else
    h2v x = __builtin_bit_cast(h2v, a), y = __builtin_bit_cast(h2v, b);
    return c + (float)x[0] * (float)y[0] + (float)x[1] * (float)y[1];
#endif
}

// ---------------------------------------------------------------------------
// Preamble: pack weights + zero halos (rows AND side cols) + scale input.
// ---------------------------------------------------------------------------
__global__ __launch_bounds__(256) void preamble_kernel(const float* __restrict__ x,
                                                       const float* __restrict__ Wmsd,
                                                       const float* __restrict__ convW,
                                                       u32* __restrict__ feats,
                                                       u32* __restrict__ wpk,
                                                       u32* __restrict__ cpk,
                                                       const float* __restrict__ sw,
                                                       const float* __restrict__ sb) {
    int idx = blockIdx.x * 256 + threadIdx.x;

    if (idx < MSD_DEPTH * NPAIR * 9) {
        int I = idx / (NPAIR * 9);
        int rem = idx - I * (NPAIR * 9);
        int p = rem / 9, t = rem - p * 9;
        int NC = I + 1, c0 = 2 * p, c1 = 2 * p + 1;
        h2v pk;
        pk[0] = (_Float16)((c0 < NC) ? Wmsd[((size_t)I * MSD_DEPTH + c0) * 9 + t] : 0.f);
        pk[1] = (_Float16)((c1 < NC) ? Wmsd[((size_t)I * MSD_DEPTH + c1) * 9 + t] : 0.f);
        wpk[idx] = __builtin_bit_cast(u32, pk);
    }
    if (idx < NPAIR) {
        h2v pk;
        pk[0] = (_Float16)convW[2 * idx];
        pk[1] = (_Float16)convW[2 * idx + 1];
        cpk[idx] = __builtin_bit_cast(u32, pk);
    }

    if (idx < ZSTRIPS) {
        const int per = 32 * (WPp / 4); // 32 rows x 136 uint4 strips
        int sub = idx / per;
        int s = idx - sub * per;
        int rr = s / 136;
        int c4 = (s - rr * 136) * 4;
        int r = (rr < 16) ? rr : (IH + HALO) + (rr - 16);
        uint4 z = {0, 0, 0, 0};
        *(uint4*)(feats + (size_t)sub * PLANE_U + (size_t)r * WPp + c4) = z;
    } else if (idx < TOTZ) {
        int s = idx - ZSTRIPS;
        int sub = s >> 12;
        int rem = s & 4095;
        int r = HALO + (rem >> 3);
        int e = rem & 7;
        int c4 = (e < 4) ? (e * 4) : (IW + HALO + (e - 4) * 4);
        uint4 z = {0, 0, 0, 0};
        *(uint4*)(feats + (size_t)sub * PLANE_U + (size_t)r * WPp + c4) = z;
    }

    if (idx < NPIX / 8) {
        int pix = idx * 8;
        int b = pix >> 18;
        int y = (pix >> 9) & 511;
        int xx = pix & 511;
        const float sws = sw[0], sbs = sb[0];
        u32 v[8];
#pragma unroll
        for (int j = 0; j < 8; ++j) {
            _Float16 h = (_Float16)(x[pix + j] * sws + sbs);
            v[j] = (u32)__builtin_bit_cast(unsigned short, h);
        }
        u32* q = feats + (size_t)b * PLANE_U + (size_t)(y + HALO) * WPp + HALO + xx;
        *(uint4*)q = *(uint4*)&v[0];
        *(uint4*)(q + 4) = *(uint4*)&v[4];
    }
}

// ---------------------------------------------------------------------------
// Fused depth-pair kernel: phase 1 = depth I (owned + halo rows -> LDS),
// phase 2 = depth I+1 (owned rows; top pair from LDS). I is even.
// ---------------------------------------------------------------------------
template <int I>
__global__ __launch_bounds__(512, 4) void fused_kernel(u32* __restrict__ feats,
                                                       const u32* __restrict__ wpk,
                                                       const u32* __restrict__ cpk,
                                                       const float* __restrict__ bias,
                                                       const float* __restrict__ convW,
                                                       const float* __restrict__ convB,
                                                       const float* __restrict__ soutw,
                                                       const float* __restrict__ soutb,
                                                       float* __restrict__ out) {
    constexpr int D1 = (I % 10) + 1;          // dilation of depth I (odd)
    constexpr int D2 = ((I + 1) % 10) + 1;    // dilation of depth I+1 (even)
    constexpr int NP = I / 2 + 1;             // pairs read by BOTH depths
    constexpr bool LAST = (I == MSD_DEPTH - 2);
    constexpr int HR = 4 + 2 * D2;            // LDS rows (owned + halo)
    constexpr int ITER = HR / 4;              // 8 waves x ITER = 2*HR half-rows
    constexpr int C01 = (12 - D1) >> 2, C11 = (15 + D1) >> 2;
    constexpr int C02 = (12 - D2) >> 2, C12 = (15 + D2) >> 2;
    constexpr int LW = 544;                   // 16 pad | 512 | 16 pad (u32)

    __shared__ u32 hl[HR][LW];

    const int tid = threadIdx.x;
    const int w = tid >> 6, lane = tid & 63;
    const int bid = blockIdx.x;               // 512 blocks
    const int xcd = bid & 7;                  // XCD band swizzle (R4-R8)
    const int kk = bid >> 3;                  // 0..63
    const int b = xcd >> 1;
    const int y0 = (xcd & 1) * 256 + kk * 4;  // first owned row

    const u32* const wrb1 = wpk + (size_t)I * (NPAIR * 9);
    const float b1 = bias[I];

    // ---------------- phase 1: depth I on rows [y0-D2, y0+4+D2) ------------
    for (int t = 0; t < ITER; ++t) {
        const int hh = w + 8 * t;             // exact: 8*ITER == 2*HR
        const int hrow = hh >> 1, half = hh & 1;
        const int row = y0 - D2 + hrow;
        const int xx = half * 256 + lane * 4;
        if (lane < 16) hl[hrow][half ? (528 + lane) : lane] = 0u;  // side pads
        if (row < 0 || row >= IH) {
#pragma unroll
            for (int j = 0; j < 4; ++j) hl[hrow][16 + xx + j] = 0u;
        } else {
            u32* const pb = feats + (size_t)b * PLANE_U +
                            (size_t)(row + HALO) * WPp + HALO + xx;
            float acc[4];
#pragma unroll
            for (int j = 0; j < 4; ++j) acc[j] = 0.f;

            u32 A[3][28], B[3][28];   // named double buffers (SROA-promoted)
            auto load_pair = [&](u32 (*bp)[28], int p) {
                const u32* pp = pb + (size_t)p * PSTR;
#pragma unroll
                for (int r = 0; r < 3; ++r) {
                    const u32* rp = pp + (ptrdiff_t)(r - 1) * (D1 * WPp);
#pragma unroll
                    for (int c = C01; c <= C11; ++c)
                        *(uint4*)&bp[r][4 * c] = *(const uint4*)(rp - 12 + 4 * c);
                }
            };
            auto compute = [&](u32 (*bp)[28], int p) {
                const u32* wq = wrb1 + p * 9;   // wave-uniform -> s_load
#pragma unroll
                for (int r = 0; r < 3; ++r) {
                    const u32* s = bp[r];
                    const u32 w0 = wq[r * 3 + 0], w1 = wq[r * 3 + 1], w2 = wq[r * 3 + 2];
#pragma unroll
                    for (int k = 0; k < 4; ++k) {
                        float a = acc[k];
                        a = fdot2u(s[12 - D1 + k], w0, a);
                        a = fdot2u(s[12 + k],      w1, a);
                        a = fdot2u(s[12 + D1 + k], w2, a);
                        acc[k] = a;
                    }
                }
            };
            load_pair(A, 0);
            int p = 0;
            for (; p + 2 <= NP; p += 2) {
                load_pair(B, p + 1);
                compute(A, p);
                if (p + 2 < NP) load_pair(A, p + 2);
                compute(B, p + 1);
            }
            if (p < NP) compute(A, p);

            // NC1 = I+1 is odd: merge h into hi16; partner lo16 = channel I
            // = center row of top pair, live in A or B (mask kills any
            // concurrently-written hi16 garbage).
            constexpr bool inA = (((NP - 1) & 1) == 0);
            const u32* sc = inA ? A[1] : B[1];
            u32 mg[4];
#pragma unroll
            for (int j = 0; j < 4; ++j) {
                float hv = acc[j] + b1;
                hv = hv > 0.f ? hv : 0.f;
                u32 h16 = (u32)__builtin_bit_cast(unsigned short, (_Float16)hv);
                mg[j] = (sc[12 + j] & 0xFFFFu) | (h16 << 16);
            }
#pragma unroll
            for (int j = 0; j < 4; ++j) hl[hrow][16 + xx + j] = mg[j];
            if constexpr (!LAST) {            // next kernel reads pair I/2
                if (row >= y0 && row < y0 + 4) {
                    u32* q = feats + (size_t)(I / 2) * PSTR + (size_t)b * PLANE_U +
                             (size_t)(row + HALO) * WPp + HALO + xx;
                    *(uint4*)q = *(uint4*)&mg[0];
                }
            }
        }
    }
    __syncthreads();

    // ---------------- phase 2: depth I+1 on owned rows ---------------------
    {
        const int y = y0 + (w >> 1);
        const int half = w & 1;
        const int xx = half * 256 + lane * 4;
        const u32* const wrb2 = wpk + (size_t)(I + 1) * (NPAIR * 9);
        u32* const pb = feats + (size_t)b * PLANE_U +
                        (size_t)(y + HALO) * WPp + HALO + xx;

        float acc[4], ydot[4];
#pragma unroll
        for (int j = 0; j < 4; ++j) { acc[j] = 0.f; ydot[j] = 0.f; }

        u32 A[3][28], B[3][28];
        auto load_pair = [&](u32 (*bp)[28], int p) {
            const u32* pp = pb + (size_t)p * PSTR;
#pragma unroll
            for (int r = 0; r < 3; ++r) {
                const u32* rp = pp + (ptrdiff_t)(r - 1) * (D2 * WPp);
#pragma unroll
                for (int c = C02; c <= C12; ++c)
                    *(uint4*)&bp[r][4 * c] = *(const uint4*)(rp - 12 + 4 * c);
            }
        };
        auto compute = [&](u32 (*bp)[28], int p) {
            const u32* wq = wrb2 + p * 9;
            const u32 cw = LAST ? cpk[p] : 0u;
#pragma unroll
            for (int r = 0; r < 3; ++r) {
                const u32* s = bp[r];
                const u32 w0 = wq[r * 3 + 0], w1 = wq[r * 3 + 1], w2 = wq[r * 3 + 2];
#pragma unroll
                for (int k = 0; k < 4; ++k) {
                    float a = acc[k];
                    a = fdot2u(s[12 - D2 + k], w0, a);
                    a = fdot2u(s[12 + k],      w1, a);
                    a = fdot2u(s[12 + D2 + k], w2, a);
                    acc[k] = a;
                }
                if (LAST && r == 1) {
#pragma unroll
                    for (int k = 0; k < 4; ++k) ydot[k] = fdot2u(s[12 + k], cw, ydot[k]);
                }
            }
        };

        // Plain pipeline over immutable global pairs [0, NP-1).
        if constexpr (NP > 1) {
            load_pair(A, 0);
            int p = 0;
            for (; p + 2 <= NP - 1; p += 2) {
                load_pair(B, p + 1);
                compute(A, p);
                if (p + 2 < NP - 1) load_pair(A, p + 2);
                compute(B, p + 1);
            }
            if (p < NP - 1) compute(A, p);
        }
        // Top pair (channel I lo | h_I hi) from LDS — zero cross-block deps.
        {
            const int lr0 = y - y0;           // rows: y-D2, y, y+D2 in LDS
            auto ldrow = [&](u32* dst, int lr) {
#pragma unroll
                for (int c = C02; c <= C12; ++c)
                    *(uint4*)&dst[4 * c] = *(const uint4*)&hl[lr][16 + xx - 12 + 4 * c];
            };
            ldrow(A[0], lr0);
            ldrow(A[1], lr0 + D2);
            ldrow(A[2], lr0 + 2 * D2);
            compute(A, NP - 1);
        }

        const float b2 = bias[I + 1];
        if constexpr (!LAST) {
            // NC2 = I+2 even: merge h into lo16 of pair (I+2)/2, hi16 = 0.
            u32 mg[4];
#pragma unroll
            for (int j = 0; j < 4; ++j) {
                float hv = acc[j] + b2;
                hv = hv > 0.f ? hv : 0.f;
                mg[j] = (u32)__builtin_bit_cast(unsigned short, (_Float16)hv);
            }
            u32* q = feats + (size_t)((I + 2) / 2) * PSTR + (size_t)b * PLANE_U +
                     (size_t)(y + HALO) * WPp + HALO + xx;
            *(uint4*)q = *(uint4*)&mg[0];
        } else {
            const float cw30 = convW[MSD_DEPTH];
            const float cb = convB[0], ow = soutw[0], ob = soutb[0];
            float* q = out + ((size_t)b * IH + y) * IW + xx;
            float o[4];
#pragma unroll
            for (int j = 0; j < 4; ++j) {
                float hv = acc[j] + b2;
                hv = hv > 0.f ? hv : 0.f;
                float yv = ydot[j] + cw30 * hv + cb;
                o[j] = yv * ow + ob;
            }
            *(uint4*)q = *(uint4*)&o[0];
        }
    }
}

// ---------------------------------------------------------------------------
extern "C" void kernel_launch(void* const* d_in, const int* in_sizes, int n_in,
                              void* d_out, int out_size, void* d_ws, size_t ws_size,
                              hipStream_t stream) {
    const float* x     = (const float*)d_in[0];
    const float* Wmsd  = (const float*)d_in[1];
    const float* bias  = (const float*)d_in[2];
    const float* convW = (const float*)d_in[3];
    const float* convB = (const float*)d_in[4];
    const float* sinw  = (const float*)d_in[5];
    const float* sinb  = (const float*)d_in[6];
    const float* soutw = (const float*)d_in[7];
    const float* soutb = (const float*)d_in[8];
    float* out = (float*)d_out;

    u32* feats = (u32*)d_ws;                 // 15 pairs x 4 b x 544x544 u32 = 71 MB
    u32* wpk = feats + WPK_OFF;              // 80 MB offset
    u32* cpk = wpk + MSD_DEPTH * NPAIR * 9;

    preamble_kernel<<<(TOTZ + 255) / 256, 256, 0, stream>>>(x, Wmsd, convW,
                                                            feats, wpk, cpk,
                                                            sinw, sinb);

#define LNCH(I) fused_kernel<I><<<512, 512, 0, stream>>>(feats, wpk, cpk, bias, convW, convB, soutw, soutb, out);
    LNCH(0)  LNCH(2)  LNCH(4)  LNCH(6)  LNCH(8)
    LNCH(10) LNCH(12) LNCH(14) LNCH(16) LNCH(18)
    LNCH(20) LNCH(22) LNCH(24) LNCH(26) LNCH(28)
#undef LNCH
}

// Round 14
// 384.479 us; speedup vs baseline: 3.8269x; 1.9255x over previous
//
#include <hip/hip_runtime.h>

// MSDNet on gfx950 — round 25: SELECTIVE cheap-pair fusion on the R18 trunk.
// R24 calibration: blanket pair-fusion added S(D2/2 x NP)=390 redundancy
// units x ~1.1-1.35us = +435us (L2 thrash -> ~2.1TB/s L3 plateau), while a
// launch only costs ~3.5-5us. Fuse ONLY pairs where redundancy < launch
// save: (0,1) u=1, (2,3) u=4, (9,10) u=2.5, (19,20) u=5  (u=(D2/2)xNP).
// Odd-J pairs generalized: h_J lands in a NEW pair's lo16 => phase 2's LDS
// pair is never read from global at all (no torn-pair concerns); merge
// parities flip (phase1: lo16 no-partner; phase2: hi16, partner = LDS
// center lo16). Remaining 22 depths: R18's verified depth4_kernel verbatim
// ((512,4), 4px/lane, partner-from-regs). Per-pixel accumulation order
// unchanged => bit-identical. 27 launches (was 31).

#define MSD_DEPTH 30
#define NB 4
#define IH 512
#define IW 512
#define HALO 16
#define WPp (IW + 2 * HALO)               /* 544 u32 per row */
#define HPp (IH + 2 * HALO)               /* 544 rows */
#define PLANE_U ((size_t)WPp * HPp)       /* u32 per subplane */
#define PSTR ((size_t)NB * PLANE_U)       /* pair stride (u32) */
#define NPAIR 15
#define NPIX (NB * IH * IW)
#define WPK_OFF ((size_t)20 << 20)        /* u32 offset: 80 MB into ws */
#define ZSTRIPS (32 * (WPp / 4) * NPAIR * NB)   /* top/bot: 261120 uint4 */
#define SSTRIPS (512 * 8 * NPAIR * NB)          /* sides:   245760 uint4 */
#define TOTZ (ZSTRIPS + SSTRIPS)

typedef _Float16 h2v __attribute__((ext_vector_type(2)));
typedef unsigned int u32;

__device__ __forceinline__ float fdot2u(u32 a, u32 b, float c) {
#if __has_builtin(__builtin_amdgcn_fdot2)
    return __builtin_amdgcn_fdot2(__builtin_bit_cast(h2v, a),
                                  __builtin_bit_cast(h2v, b), c, false);
#else
    h2v x = __builtin_bit_cast(h2v, a), y = __builtin_bit_cast(h2v, b);
    return c + (float)x[0] * (float)y[0] + (float)x[1] * (float)y[1];
#endif
}

// ---------------------------------------------------------------------------
// Preamble: pack weights + zero halos (rows AND side cols) + scale input.
// ---------------------------------------------------------------------------
__global__ __launch_bounds__(256) void preamble_kernel(const float* __restrict__ x,
                                                       const float* __restrict__ Wmsd,
                                                       const float* __restrict__ convW,
                                                       u32* __restrict__ feats,
                                                       u32* __restrict__ wpk,
                                                       u32* __restrict__ cpk,
                                                       const float* __restrict__ sw,
                                                       const float* __restrict__ sb) {
    int idx = blockIdx.x * 256 + threadIdx.x;

    if (idx < MSD_DEPTH * NPAIR * 9) {
        int I = idx / (NPAIR * 9);
        int rem = idx - I * (NPAIR * 9);
        int p = rem / 9, t = rem - p * 9;
        int NC = I + 1, c0 = 2 * p, c1 = 2 * p + 1;
        h2v pk;
        pk[0] = (_Float16)((c0 < NC) ? Wmsd[((size_t)I * MSD_DEPTH + c0) * 9 + t] : 0.f);
        pk[1] = (_Float16)((c1 < NC) ? Wmsd[((size_t)I * MSD_DEPTH + c1) * 9 + t] : 0.f);
        wpk[idx] = __builtin_bit_cast(u32, pk);
    }
    if (idx < NPAIR) {
        h2v pk;
        pk[0] = (_Float16)convW[2 * idx];
        pk[1] = (_Float16)convW[2 * idx + 1];
        cpk[idx] = __builtin_bit_cast(u32, pk);
    }

    if (idx < ZSTRIPS) {
        const int per = 32 * (WPp / 4); // 32 rows x 136 uint4 strips
        int sub = idx / per;
        int s = idx - sub * per;
        int rr = s / 136;
        int c4 = (s - rr * 136) * 4;
        int r = (rr < 16) ? rr : (IH + HALO) + (rr - 16);
        uint4 z = {0, 0, 0, 0};
        *(uint4*)(feats + (size_t)sub * PLANE_U + (size_t)r * WPp + c4) = z;
    } else if (idx < TOTZ) {
        int s = idx - ZSTRIPS;
        int sub = s >> 12;
        int rem = s & 4095;
        int r = HALO + (rem >> 3);
        int e = rem & 7;
        int c4 = (e < 4) ? (e * 4) : (IW + HALO + (e - 4) * 4);
        uint4 z = {0, 0, 0, 0};
        *(uint4*)(feats + (size_t)sub * PLANE_U + (size_t)r * WPp + c4) = z;
    }

    if (idx < NPIX / 8) {
        int pix = idx * 8;
        int b = pix >> 18;
        int y = (pix >> 9) & 511;
        int xx = pix & 511;
        const float sws = sw[0], sbs = sb[0];
        u32 v[8];
#pragma unroll
        for (int j = 0; j < 8; ++j) {
            _Float16 h = (_Float16)(x[pix + j] * sws + sbs);
            v[j] = (u32)__builtin_bit_cast(unsigned short, h);
        }
        u32* q = feats + (size_t)b * PLANE_U + (size_t)(y + HALO) * WPp + HALO + xx;
        *(uint4*)q = *(uint4*)&v[0];
        *(uint4*)(q + 4) = *(uint4*)&v[4];
    }
}

// ---------------------------------------------------------------------------
// Single-depth kernel — R18 verbatim (4 px/lane, (512,4), verified 380.6us).
// ---------------------------------------------------------------------------
template <int I>
__global__ __launch_bounds__(512, 4) void depth4_kernel(u32* __restrict__ feats,
                                                        const u32* __restrict__ wpk,
                                                        const u32* __restrict__ cpk,
                                                        const float* __restrict__ bias,
                                                        const float* __restrict__ convW,
                                                        const float* __restrict__ convB,
                                                        const float* __restrict__ soutw,
                                                        const float* __restrict__ soutb,
                                                        float* __restrict__ out) {
    constexpr int D = (I % 10) + 1;
    constexpr int NC = I + 1;
    constexpr int NP = (NC + 1) / 2;
    constexpr bool LAST = (I == MSD_DEPTH - 1);
    constexpr int C0 = (12 - D) >> 2;
    constexpr int C1 = (15 + D) >> 2;

    const int tid = threadIdx.x;
    const int widx = tid >> 6, lane = tid & 63;
    const int bid = blockIdx.x;
    const int xcd = bid & 7;            // XCD band swizzle (validated R4-R8)
    const int kk = bid >> 3;
    const int b = xcd >> 1;
    const int y = (xcd & 1) * 256 + kk * 4 + (widx >> 1);
    const int h = widx & 1;
    const int xx = h * 256 + lane * 4;

    u32* const pb = feats + (size_t)b * PLANE_U + (size_t)(y + HALO) * WPp + HALO + xx;

    float acc[4], ydot[4];
#pragma unroll
    for (int j = 0; j < 4; ++j) { acc[j] = 0.f; ydot[j] = 0.f; }

    const u32* const wrb = wpk + (size_t)I * (NPAIR * 9);

    u32 A[3][28], B[3][28];

    auto load_pair = [&](u32 (*bp)[28], int p) {
        const u32* pp = pb + (size_t)p * PSTR;
#pragma unroll
        for (int r = 0; r < 3; ++r) {
            const u32* rp = pp + (ptrdiff_t)(r - 1) * (D * WPp);
#pragma unroll
            for (int c = C0; c <= C1; ++c)
                *(uint4*)&bp[r][4 * c] = *(const uint4*)(rp - 12 + 4 * c);
        }
    };

    auto compute = [&](u32 (*bp)[28], int p) {
        const u32* wq = wrb + p * 9;
        const u32 cw = LAST ? cpk[p] : 0u;
#pragma unroll
        for (int r = 0; r < 3; ++r) {
            const u32* s = bp[r];
            const u32 w0 = wq[r * 3 + 0], w1 = wq[r * 3 + 1], w2 = wq[r * 3 + 2];
#pragma unroll
            for (int k = 0; k < 4; ++k) {
                float a = acc[k];
                a = fdot2u(s[12 - D + k], w0, a);
                a = fdot2u(s[12 + k],     w1, a);
                a = fdot2u(s[12 + D + k], w2, a);
                acc[k] = a;
            }
            if (LAST && r == 1) {
#pragma unroll
                for (int k = 0; k < 4; ++k) ydot[k] = fdot2u(s[12 + k], cw, ydot[k]);
            }
        }
    };

    load_pair(A, 0);
    int p = 0;
    for (; p + 2 <= NP; p += 2) {
        load_pair(B, p + 1);
        compute(A, p);
        if (p + 2 < NP) load_pair(A, p + 2);
        compute(B, p + 1);
    }
    if (p < NP) compute(A, p);

    const float b0 = bias[I];
    if (!LAST) {
        u32 part[4];
        if constexpr ((NC & 1) != 0) {
            constexpr bool inA = (((NP - 1) & 1) == 0);
            const u32* s = inA ? A[1] : B[1];
#pragma unroll
            for (int j = 0; j < 4; ++j) part[j] = s[12 + j];
        }
        u32 mg[4];
#pragma unroll
        for (int j = 0; j < 4; ++j) {
            float hh = acc[j] + b0;
            hh = hh > 0.f ? hh : 0.f;
            u32 h16 = (u32)__builtin_bit_cast(unsigned short, (_Float16)hh);
            if constexpr ((NC & 1) != 0)
                mg[j] = (part[j] & 0xFFFFu) | (h16 << 16);
            else
                mg[j] = h16;
        }
        u32* q = feats + (size_t)(NC >> 1) * PSTR + (size_t)b * PLANE_U +
                 (size_t)(y + HALO) * WPp + HALO + xx;
        *(uint4*)q = *(uint4*)&mg[0];
    } else {
        const float cw30 = convW[MSD_DEPTH];
        const float cb = convB[0], ow = soutw[0], ob = soutb[0];
        float* q = out + ((size_t)b * IH + y) * IW + xx;
        float o[4];
#pragma unroll
        for (int j = 0; j < 4; ++j) {
            float hh = acc[j] + b0;
            hh = hh > 0.f ? hh : 0.f;
            float yv = ydot[j] + cw30 * hh + cb;
            o[j] = yv * ow + ob;
        }
        *(uint4*)q = *(uint4*)&o[0];
    }
}

// ---------------------------------------------------------------------------
// Fused depth-pair kernel (J, J+1), both parities. Phase 1 = depth J on
// owned + 2*D2 halo rows -> LDS (+ owned rows to global). Phase 2 = depth
// J+1 on owned rows; top pair from LDS (zero cross-block dependencies).
// Never the LAST depth (J+1 <= 20 in our selection).
// ---------------------------------------------------------------------------
template <int J>
__global__ __launch_bounds__(512, 4) void fused_kernel(u32* __restrict__ feats,
                                                       const u32* __restrict__ wpk,
                                                       const float* __restrict__ bias) {
    constexpr int D1 = (J % 10) + 1;
    constexpr int D2 = ((J + 1) % 10) + 1;
    constexpr int NP1 = (J + 2) / 2;          // pairs read by phase 1
    constexpr int NP2 = (J + 3) / 2;          // pairs read by phase 2
    constexpr bool ODDJ = (J & 1) != 0;
    constexpr int PW = (J + 1) / 2;           // pair written by phase 1
    constexpr int HR = 4 + 2 * D2;            // LDS rows
    constexpr int NIT = (2 * HR + 7) / 8;
    constexpr int C01 = (12 - D1) >> 2, C11 = (15 + D1) >> 2;
    constexpr int C02 = (12 - D2) >> 2, C12 = (15 + D2) >> 2;

    __shared__ u32 hl[HR][544];               // 16 pad | 512 | 16 pad

    const int tid = threadIdx.x;
    const int w = tid >> 6, lane = tid & 63;
    const int bid = blockIdx.x;
    const int xcd = bid & 7;                  // XCD band swizzle (R4-R8)
    const int kk = bid >> 3;
    const int b = xcd >> 1;
    const int y0 = (xcd & 1) * 256 + kk * 4;  // first owned row

    const u32* const wrb1 = wpk + (size_t)J * (NPAIR * 9);
    const float b1 = bias[J];

    // ---------------- phase 1: depth J on rows [y0-D2, y0+4+D2) ------------
    for (int t = 0; t < NIT; ++t) {
        const int hh = w + 8 * t;             // wave-uniform
        if (hh >= 2 * HR) break;
        const int hrow = hh >> 1, half = hh & 1;
        const int row = y0 - D2 + hrow;
        const int xx = half * 256 + lane * 4;
        if (lane < 16) hl[hrow][half ? (528 + lane) : lane] = 0u;  // side pads
        if (row < 0 || row >= IH) {
#pragma unroll
            for (int j = 0; j < 4; ++j) hl[hrow][16 + xx + j] = 0u;
        } else {
            u32* const pb = feats + (size_t)b * PLANE_U +
                            (size_t)(row + HALO) * WPp + HALO + xx;
            float acc[4];
#pragma unroll
            for (int j = 0; j < 4; ++j) acc[j] = 0.f;

            u32 A[3][28], B[3][28];
            auto load_pair = [&](u32 (*bp)[28], int p) {
                const u32* pp = pb + (size_t)p * PSTR;
#pragma unroll
                for (int r = 0; r < 3; ++r) {
                    const u32* rp = pp + (ptrdiff_t)(r - 1) * (D1 * WPp);
#pragma unroll
                    for (int c = C01; c <= C11; ++c)
                        *(uint4*)&bp[r][4 * c] = *(const uint4*)(rp - 12 + 4 * c);
                }
            };
            auto compute = [&](u32 (*bp)[28], int p) {
                const u32* wq = wrb1 + p * 9;
#pragma unroll
                for (int r = 0; r < 3; ++r) {
                    const u32* s = bp[r];
                    const u32 w0 = wq[r * 3 + 0], w1 = wq[r * 3 + 1], w2 = wq[r * 3 + 2];
#pragma unroll
                    for (int k = 0; k < 4; ++k) {
                        float a = acc[k];
                        a = fdot2u(s[12 - D1 + k], w0, a);
                        a = fdot2u(s[12 + k],      w1, a);
                        a = fdot2u(s[12 + D1 + k], w2, a);
                        acc[k] = a;
                    }
                }
            };
            load_pair(A, 0);
            int p = 0;
            for (; p + 2 <= NP1; p += 2) {
                load_pair(B, p + 1);
                compute(A, p);
                if (p + 2 < NP1) load_pair(A, p + 2);
                compute(B, p + 1);
            }
            if (p < NP1) compute(A, p);

            u32 mg[4];
            if constexpr (!ODDJ) {
                // channel J+1 odd -> hi16; partner lo16 = channel J = center
                // row of top phase-1 pair, live in regs (mask kills any
                // concurrently-written hi16 garbage).
                constexpr bool inA = (((NP1 - 1) & 1) == 0);
                const u32* sc = inA ? A[1] : B[1];
#pragma unroll
                for (int j = 0; j < 4; ++j) {
                    float hv = acc[j] + b1;
                    hv = hv > 0.f ? hv : 0.f;
                    u32 h16 = (u32)__builtin_bit_cast(unsigned short, (_Float16)hv);
                    mg[j] = (sc[12 + j] & 0xFFFFu) | (h16 << 16);
                }
            } else {
                // channel J+1 even -> lo16 of a NEW pair, hi16 = 0.
#pragma unroll
                for (int j = 0; j < 4; ++j) {
                    float hv = acc[j] + b1;
                    hv = hv > 0.f ? hv : 0.f;
                    mg[j] = (u32)__builtin_bit_cast(unsigned short, (_Float16)hv);
                }
            }
#pragma unroll
            for (int j = 0; j < 4; ++j) hl[hrow][16 + xx + j] = mg[j];
            if (row >= y0 && row < y0 + 4) {   // owned rows -> global
                u32* q = feats + (size_t)PW * PSTR + (size_t)b * PLANE_U +
                         (size_t)(row + HALO) * WPp + HALO + xx;
                *(uint4*)q = *(uint4*)&mg[0];
            }
        }
    }
    __syncthreads();

    // ---------------- phase 2: depth J+1 on owned rows ---------------------
    {
        const int y = y0 + (w >> 1);
        const int half = w & 1;
        const int xx = half * 256 + lane * 4;
        const u32* const wrb2 = wpk + (size_t)(J + 1) * (NPAIR * 9);
        u32* const pb = feats + (size_t)b * PLANE_U +
                        (size_t)(y + HALO) * WPp + HALO + xx;

        float acc[4];
#pragma unroll
        for (int j = 0; j < 4; ++j) acc[j] = 0.f;

        u32 A[3][28], B[3][28];
        auto load_pair = [&](u32 (*bp)[28], int p) {
            const u32* pp = pb + (size_t)p * PSTR;
#pragma unroll
            for (int r = 0; r < 3; ++r) {
                const u32* rp = pp + (ptrdiff_t)(r - 1) * (D2 * WPp);
#pragma unroll
                for (int c = C02; c <= C12; ++c)
                    *(uint4*)&bp[r][4 * c] = *(const uint4*)(rp - 12 + 4 * c);
            }
        };
        auto compute = [&](u32 (*bp)[28], int p) {
            const u32* wq = wrb2 + p * 9;
#pragma unroll
            for (int r = 0; r < 3; ++r) {
                const u32* s = bp[r];
                const u32 w0 = wq[r * 3 + 0], w1 = wq[r * 3 + 1], w2 = wq[r * 3 + 2];
#pragma unroll
                for (int k = 0; k < 4; ++k) {
                    float a = acc[k];
                    a = fdot2u(s[12 - D2 + k], w0, a);
                    a = fdot2u(s[12 + k],      w1, a);
                    a = fdot2u(s[12 + D2 + k], w2, a);
                    acc[k] = a;
                }
            }
        };

        // Plain pipeline over immutable global pairs [0, NP2-1).
        if constexpr (NP2 > 1) {
            load_pair(A, 0);
            int p = 0;
            for (; p + 2 <= NP2 - 1; p += 2) {
                load_pair(B, p + 1);
                compute(A, p);
                if (p + 2 < NP2 - 1) load_pair(A, p + 2);
                compute(B, p + 1);
            }
            if (p < NP2 - 1) compute(A, p);
        }
        // Top pair from LDS — zero cross-block dependencies.
        {
            const int lr0 = y - y0;           // rows y-D2, y, y+D2 in LDS
            auto ldrow = [&](u32* dst, int lr) {
#pragma unroll
                for (int c = C02; c <= C12; ++c)
                    *(uint4*)&dst[4 * c] = *(const uint4*)&hl[lr][16 + xx - 12 + 4 * c];
            };
            ldrow(A[0], lr0);
            ldrow(A[1], lr0 + D2);
            ldrow(A[2], lr0 + 2 * D2);
            compute(A, NP2 - 1);
        }

        // Merge h_{J+1} (channel J+2) into pair (J+2)/2.
        const float b2 = bias[J + 1];
        u32 mg[4];
        if constexpr (ODDJ) {
            // channel J+2 odd -> hi16; partner lo16 = channel J+1 = LDS top
            // pair center row lo16 (in regs A[1]).
#pragma unroll
            for (int j = 0; j < 4; ++j) {
                float hv = acc[j] + b2;
                hv = hv > 0.f ? hv : 0.f;
                u32 h16 = (u32)__builtin_bit_cast(unsigned short, (_Float16)hv);
                mg[j] = (A[1][12 + j] & 0xFFFFu) | (h16 << 16);
            }
        } else {
            // channel J+2 even -> lo16 of new pair, hi16 = 0.
#pragma unroll
            for (int j = 0; j < 4; ++j) {
                float hv = acc[j] + b2;
                hv = hv > 0.f ? hv : 0.f;
                mg[j] = (u32)__builtin_bit_cast(unsigned short, (_Float16)hv);
            }
        }
        u32* q = feats + (size_t)((J + 2) / 2) * PSTR + (size_t)b * PLANE_U +
                 (size_t)(y + HALO) * WPp + HALO + xx;
        *(uint4*)q = *(uint4*)&mg[0];
    }
}

// ---------------------------------------------------------------------------
extern "C" void kernel_launch(void* const* d_in, const int* in_sizes, int n_in,
                              void* d_out, int out_size, void* d_ws, size_t ws_size,
                              hipStream_t stream) {
    const float* x     = (const float*)d_in[0];
    const float* Wmsd  = (const float*)d_in[1];
    const float* bias  = (const float*)d_in[2];
    const float* convW = (const float*)d_in[3];
    const float* convB = (const float*)d_in[4];
    const float* sinw  = (const float*)d_in[5];
    const float* sinb  = (const float*)d_in[6];
    const float* soutw = (const float*)d_in[7];
    const float* soutb = (const float*)d_in[8];
    float* out = (float*)d_out;

    u32* feats = (u32*)d_ws;                 // 15 pairs x 4 b x 544x544 u32 = 71 MB
    u32* wpk = feats + WPK_OFF;              // 80 MB offset
    u32* cpk = wpk + MSD_DEPTH * NPAIR * 9;

    preamble_kernel<<<(TOTZ + 255) / 256, 256, 0, stream>>>(x, Wmsd, convW,
                                                            feats, wpk, cpk,
                                                            sinw, sinb);

#define FUSE(J) fused_kernel<J><<<512, 512, 0, stream>>>(feats, wpk, bias);
#define SNGL(I) depth4_kernel<I><<<512, 512, 0, stream>>>(feats, wpk, cpk, bias, convW, convB, soutw, soutb, out);
    FUSE(0)            /* depths 0,1  (D2=2, NP=1)  */
    FUSE(2)            /* depths 2,3  (D2=4, NP=2)  */
    SNGL(4)  SNGL(5)  SNGL(6)  SNGL(7)  SNGL(8)
    FUSE(9)            /* depths 9,10 (D2=1, NP=5)  */
    SNGL(11) SNGL(12) SNGL(13) SNGL(14) SNGL(15)
    SNGL(16) SNGL(17) SNGL(18)
    FUSE(19)           /* depths 19,20 (D2=1, NP=10) */
    SNGL(21) SNGL(22) SNGL(23) SNGL(24) SNGL(25)
    SNGL(26) SNGL(27) SNGL(28) SNGL(29)
#undef FUSE
#undef SNGL
}